// Round 1
// baseline (116.693 us; speedup 1.0000x reference)
//
#include <hip/hip_runtime.h>
#include <hip/hip_bf16.h>

// Problem constants
#define B_ROWS 4096
#define N_ROWS 8192
#define D_DIM 256
#define TEMP_INV 2.0f     // 1/0.5
#define PHI 0.95f
#define SHIFT 2.0f        // sim in [-2,2]; fixed logsumexp shift

// Tiling
#define BN 64                       // columns staged per LDS tile
#define LDS_STRIDE 264              // bf16 elems; 528 B = 132 dwords == 4 mod 32 -> 2-way (free)
#define COL_SPLITS 8                // grid.y; 8192/8 = 1024 cols per block
#define COLS_PER_BLOCK (N_ROWS / COL_SPLITS)

typedef __attribute__((ext_vector_type(8))) short short8;    // 8 x bf16 = 16 B (4 VGPRs)
typedef __attribute__((ext_vector_type(4))) float floatx4;   // MFMA C/D

static __device__ __forceinline__ unsigned short f2bf(float f) {
    unsigned u = __builtin_bit_cast(unsigned, f);
    unsigned r = (u + 0x7fffu + ((u >> 16) & 1u)) >> 16;   // RNE
    return (unsigned short)r;
}

// Kernel 1: normalize rows of cat(unbind(features,1),0) -> bf16 X[8192][256];
// zero S[8192] and the output accumulator.
__global__ __launch_bounds__(256) void normalize_kernel(
        const float* __restrict__ feat, unsigned short* __restrict__ X,
        float* __restrict__ S, float* __restrict__ out) {
    int row  = blockIdx.x * 4 + (threadIdx.x >> 6);  // 4 rows per block
    int lane = threadIdx.x & 63;
    int view = row >> 12;          // 0: features[:,0,:], 1: features[:,1,:]
    int i    = row & (B_ROWS - 1);
    const float* src = feat + (size_t)i * (2 * D_DIM) + view * D_DIM;
    float4 v = ((const float4*)src)[lane];             // 4 floats/lane * 64 = 256
    float ss = v.x * v.x + v.y * v.y + v.z * v.z + v.w * v.w;
    #pragma unroll
    for (int off = 32; off; off >>= 1) ss += __shfl_xor(ss, off);
    float inv = 1.0f / fmaxf(sqrtf(ss), 1e-12f);
    ushort4 o;
    o.x = f2bf(v.x * inv); o.y = f2bf(v.y * inv);
    o.z = f2bf(v.z * inv); o.w = f2bf(v.w * inv);
    ((ushort4*)(X + (size_t)row * D_DIM))[lane] = o;   // 8 B/lane, coalesced
    if (lane == 0) S[row] = 0.0f;
    if (blockIdx.x == 0 && threadIdx.x == 0) out[0] = 0.0f;
}

// Kernel 2: per block: 64 rows x 1024 cols of sim = 2*clip(Xr . Xc, -1, 1),
// masked exp-sum (fixed shift 2) accumulated into S via atomics; pos logit -> P.
__global__ __launch_bounds__(256) void sim_lse_kernel(
        const unsigned short* __restrict__ X,
        float* __restrict__ S, float* __restrict__ P) {
    __shared__ unsigned short tile[BN * LDS_STRIDE];   // 33,792 B

    const int tid  = threadIdx.x;
    const int wave = tid >> 6;
    const int lane = tid & 63;
    const int quad = lane >> 4;    // 0..3
    const int l16  = lane & 15;

    const int rowblk = blockIdx.x;         // 0..127
    const int cbase0 = blockIdx.y * COLS_PER_BLOCK;

    // A fragments: lane holds A[m = l16][k = quad*8 + j] for each of 8 K-steps.
    const int arow = rowblk * 64 + wave * 16 + l16;
    short8 afrag[8];
    {
        const unsigned short* ap = X + (size_t)arow * D_DIM + quad * 8;
        #pragma unroll
        for (int ks = 0; ks < 8; ks++)
            afrag[ks] = *(const short8*)(ap + ks * 32);
    }

    // This lane's C rows: rowblk*64 + wave*16 + quad*4 + reg
    const int crow0 = rowblk * 64 + wave * 16 + quad * 4;
    float sacc[4] = {0.f, 0.f, 0.f, 0.f};

    for (int ct = 0; ct < COLS_PER_BLOCK / BN; ct++) {
        const int cbase = cbase0 + ct * BN;
        __syncthreads();
        // Stage 64 cols x 512 B into LDS (padded rows). 256 thr x 16 B x 8 passes.
        #pragma unroll
        for (int p = 0; p < 8; p++) {
            int idx = p * 256 + tid;
            int r   = idx >> 5;        // 0..63
            int ch  = idx & 31;        // 16-B chunk within the row
            short8 d = *(const short8*)(X + (size_t)(cbase + r) * D_DIM + ch * 8);
            *(short8*)(tile + r * LDS_STRIDE + ch * 8) = d;
        }
        __syncthreads();

        #pragma unroll
        for (int st = 0; st < 4; st++) {            // 4 sub-tiles of 16 cols
            const unsigned short* bp = tile + (st * 16 + l16) * LDS_STRIDE + quad * 8;
            floatx4 acc = {0.f, 0.f, 0.f, 0.f};
            #pragma unroll
            for (int ks = 0; ks < 8; ks++) {        // K = 256 = 8 x 32
                short8 bfrag = *(const short8*)(bp + ks * 32);
                acc = __builtin_amdgcn_mfma_f32_16x16x32_bf16(afrag[ks], bfrag, acc, 0, 0, 0);
            }
            const int col = cbase + st * 16 + l16;  // C/D: col = lane&15
            #pragma unroll
            for (int reg = 0; reg < 4; reg++) {     // C/D: row = quad*4 + reg
                const int r_c = crow0 + reg;
                float raw = fminf(fmaxf(acc[reg], -1.0f), 1.0f);
                float sim = raw * TEMP_INV;
                bool is_pos = (col == ((r_c + B_ROWS) & (N_ROWS - 1)));
                if (is_pos) P[r_c] = sim;           // unique writer globally
                bool allowed = (col != r_c) && (is_pos || raw < PHI);
                sacc[reg] += allowed ? __expf(sim - SHIFT) : 0.0f;
            }
        }
    }

    // Reduce over the 16 lanes (cols) sharing each quad, then one atomic per row.
    #pragma unroll
    for (int reg = 0; reg < 4; reg++) {
        float v = sacc[reg];
        v += __shfl_xor(v, 1);
        v += __shfl_xor(v, 2);
        v += __shfl_xor(v, 4);
        v += __shfl_xor(v, 8);
        sacc[reg] = v;
    }
    if (l16 < 4) atomicAdd(&S[crow0 + l16], sacc[l16]);
}

// Kernel 3: loss = mean(2 + log(S_i) - P_i)
__global__ __launch_bounds__(256) void finalize_kernel(
        const float* __restrict__ S, const float* __restrict__ P,
        float* __restrict__ out) {
    __shared__ float red[4];
    int i = blockIdx.x * 256 + threadIdx.x;
    float v = SHIFT + logf(S[i]) - P[i];
    #pragma unroll
    for (int off = 32; off; off >>= 1) v += __shfl_xor(v, off);
    int lane = threadIdx.x & 63, wave = threadIdx.x >> 6;
    if (lane == 0) red[wave] = v;
    __syncthreads();
    if (threadIdx.x == 0) {
        float t = red[0] + red[1] + red[2] + red[3];
        atomicAdd(out, t * (1.0f / (float)N_ROWS));
    }
}

extern "C" void kernel_launch(void* const* d_in, const int* in_sizes, int n_in,
                              void* d_out, int out_size, void* d_ws, size_t ws_size,
                              hipStream_t stream) {
    const float* feat = (const float*)d_in[0];
    float* out = (float*)d_out;

    // Workspace layout: X bf16 [8192*256] (4 MB), S f32[8192], P f32[8192]
    unsigned short* X = (unsigned short*)d_ws;
    float* S = (float*)((char*)d_ws + (size_t)N_ROWS * D_DIM * 2);
    float* P = S + N_ROWS;

    normalize_kernel<<<N_ROWS / 4, 256, 0, stream>>>(feat, X, S, out);
    sim_lse_kernel<<<dim3(N_ROWS / 64, COL_SPLITS), 256, 0, stream>>>(X, S, P);
    finalize_kernel<<<N_ROWS / 256, 256, 0, stream>>>(S, P, out);
}

// Round 2
// 106.603 us; speedup vs baseline: 1.0947x; 1.0947x over previous
//
#include <hip/hip_runtime.h>
#include <hip/hip_bf16.h>

// Problem constants
#define B_ROWS 4096
#define N_ROWS 8192
#define D_DIM 256
#define PHI 0.95f
// exp(sim-2) = exp2((2*raw-2)*log2e) = exp2(raw*C1 - C1)
#define C1 2.8853900817779268f

// Tiling: block = 4 waves x 64 rows = 256 rows; 16 col-splits x 512 cols
#define BN 64
#define LDS_STRIDE 264              // shorts; 33 chunks of 16B per row
#define COL_SPLITS 16
#define COLS_PER_BLOCK (N_ROWS / COL_SPLITS)   // 512
#define ROWS_PER_BLOCK 256

typedef __attribute__((ext_vector_type(8))) short short8;    // 8 x bf16
typedef __attribute__((ext_vector_type(4))) float floatx4;   // MFMA C/D

static __device__ __forceinline__ unsigned short f2bf(float f) {
    unsigned u = __builtin_bit_cast(unsigned, f);
    unsigned r = (u + 0x7fffu + ((u >> 16) & 1u)) >> 16;   // RNE
    return (unsigned short)r;
}
static __device__ __forceinline__ float bf2f(unsigned short s) {
    unsigned u = ((unsigned)s) << 16;
    return __builtin_bit_cast(float, u);
}
static __device__ __forceinline__ float fast_exp2(float x) {
#if __has_builtin(__builtin_amdgcn_exp2f)
    return __builtin_amdgcn_exp2f(x);
#else
    return __expf(x * 0.6931471805599453f);
#endif
}

// Kernel 1: normalize rows of cat(unbind(features,1),0) -> bf16 X[8192][256];
// zero S and out.
__global__ __launch_bounds__(256) void normalize_kernel(
        const float* __restrict__ feat, unsigned short* __restrict__ X,
        float* __restrict__ S, float* __restrict__ out) {
    int row  = blockIdx.x * 4 + (threadIdx.x >> 6);
    int lane = threadIdx.x & 63;
    int view = row >> 12;
    int i    = row & (B_ROWS - 1);
    const float* src = feat + (size_t)i * (2 * D_DIM) + view * D_DIM;
    float4 v = ((const float4*)src)[lane];
    float ss = v.x * v.x + v.y * v.y + v.z * v.z + v.w * v.w;
    #pragma unroll
    for (int off = 32; off; off >>= 1) ss += __shfl_xor(ss, off);
    float inv = 1.0f / fmaxf(sqrtf(ss), 1e-12f);
    ushort4 o;
    o.x = f2bf(v.x * inv); o.y = f2bf(v.y * inv);
    o.z = f2bf(v.z * inv); o.w = f2bf(v.w * inv);
    ((ushort4*)(X + (size_t)row * D_DIM))[lane] = o;
    if (lane == 0) S[row] = 0.0f;
    if (blockIdx.x == 0 && threadIdx.x == 0) out[0] = 0.0f;
}

// Kernel 2: rawp[i] = dot(x_i, x_{(i+B)%N})  (fp32, unclipped)
__global__ __launch_bounds__(256) void pos_kernel(
        const unsigned short* __restrict__ X, float* __restrict__ rawp) {
    int row  = blockIdx.x * 4 + (threadIdx.x >> 6);
    int lane = threadIdx.x & 63;
    int par  = (row + B_ROWS) & (N_ROWS - 1);
    ushort4 a = ((const ushort4*)(X + (size_t)row * D_DIM))[lane];
    ushort4 b = ((const ushort4*)(X + (size_t)par * D_DIM))[lane];
    float d = bf2f(a.x) * bf2f(b.x) + bf2f(a.y) * bf2f(b.y)
            + bf2f(a.z) * bf2f(b.z) + bf2f(a.w) * bf2f(b.w);
    #pragma unroll
    for (int off = 32; off; off >>= 1) d += __shfl_xor(d, off);
    if (lane == 0) rawp[row] = d;
}

// Kernel 3: Gram tile + masked exp-sum. Wave = 64 rows (A in regs), block =
// 256 rows x 512 cols. Sum_{cols, raw<phi} exp(2*raw-2) -> atomicAdd S[row].
__global__ __launch_bounds__(256, 2) void sim_lse_kernel(
        const unsigned short* __restrict__ X, float* __restrict__ S) {
    __shared__ unsigned short tile[BN * LDS_STRIDE];   // 33,792 B

    const int tid  = threadIdx.x;
    const int wave = tid >> 6;
    const int lane = tid & 63;
    const int quad = lane >> 4;    // 0..3
    const int l16  = lane & 15;

    const int rowbase = blockIdx.x * ROWS_PER_BLOCK + wave * 64;
    const int cbase0  = blockIdx.y * COLS_PER_BLOCK;

    // A fragments: 4 row-sets x 8 K-steps; lane holds A[m=l16][k=quad*8+j]
    short8 af[4][8];
    #pragma unroll
    for (int s = 0; s < 4; s++) {
        const unsigned short* ap = X + (size_t)(rowbase + s * 16 + l16) * D_DIM + quad * 8;
        #pragma unroll
        for (int ks = 0; ks < 8; ks++)
            af[s][ks] = *(const short8*)(ap + ks * 32);
    }

    float sacc[4][4];
    #pragma unroll
    for (int s = 0; s < 4; s++)
        #pragma unroll
        for (int r = 0; r < 4; r++) sacc[s][r] = 0.0f;

    for (int ct = 0; ct < COLS_PER_BLOCK / BN; ct++) {
        const int cbase = cbase0 + ct * BN;
        __syncthreads();
        #pragma unroll
        for (int p = 0; p < 8; p++) {
            int idx = p * 256 + tid;
            int r   = idx >> 5;
            int ch  = idx & 31;
            short8 d = *(const short8*)(X + (size_t)(cbase + r) * D_DIM + ch * 8);
            *(short8*)(tile + r * LDS_STRIDE + ch * 8) = d;
        }
        __syncthreads();

        #pragma unroll
        for (int st = 0; st < 4; st++) {            // 4 sub-tiles of 16 cols
            const unsigned short* bp = tile + (st * 16 + l16) * LDS_STRIDE + quad * 8;
            floatx4 acc[4];
            #pragma unroll
            for (int s = 0; s < 4; s++) acc[s] = (floatx4){0.f, 0.f, 0.f, 0.f};
            #pragma unroll
            for (int ks = 0; ks < 8; ks++) {        // K = 256
                short8 bfrag = *(const short8*)(bp + ks * 32);
                #pragma unroll
                for (int s = 0; s < 4; s++)
                    acc[s] = __builtin_amdgcn_mfma_f32_16x16x32_bf16(af[s][ks], bfrag, acc[s], 0, 0, 0);
            }
            // Epilogue: 5 VALU/elem. raw<phi excludes diag and phi-filtered
            // negatives; pos term (if ever >= phi) restored in finalize.
            #pragma unroll
            for (int s = 0; s < 4; s++)
                #pragma unroll
                for (int r = 0; r < 4; r++) {
                    float raw = acc[s][r];
                    float e = fast_exp2(fmaf(raw, C1, -C1));
                    sacc[s][r] += (raw < PHI) ? e : 0.0f;
                }
        }
    }

    // Reduce over the 16 lanes (cols) of each quad-group, one atomic per row.
    #pragma unroll
    for (int s = 0; s < 4; s++)
        #pragma unroll
        for (int r = 0; r < 4; r++) {
            float v = sacc[s][r];
            v += __shfl_xor(v, 1);
            v += __shfl_xor(v, 2);
            v += __shfl_xor(v, 4);
            v += __shfl_xor(v, 8);
            if (l16 == r) atomicAdd(&S[rowbase + s * 16 + quad * 4 + r], v);
        }
}

// Kernel 4: loss = mean(2 + log(S_i + pos-correction) - P_i)
__global__ __launch_bounds__(256) void finalize_kernel(
        const float* __restrict__ S, const float* __restrict__ rawp,
        float* __restrict__ out) {
    __shared__ float red[4];
    int i = blockIdx.x * 256 + threadIdx.x;
    float rp = rawp[i];
    float pclip = fminf(fmaxf(rp, -1.0f), 1.0f);
    float psim = 2.0f * pclip;
    float Sv = S[i] + ((rp >= PHI) ? __expf(psim - 2.0f) : 0.0f);
    float v = 2.0f + logf(Sv) - psim;
    #pragma unroll
    for (int off = 32; off; off >>= 1) v += __shfl_xor(v, off);
    int lane = threadIdx.x & 63, wave = threadIdx.x >> 6;
    if (lane == 0) red[wave] = v;
    __syncthreads();
    if (threadIdx.x == 0) {
        float t = red[0] + red[1] + red[2] + red[3];
        atomicAdd(out, t * (1.0f / (float)N_ROWS));
    }
}

extern "C" void kernel_launch(void* const* d_in, const int* in_sizes, int n_in,
                              void* d_out, int out_size, void* d_ws, size_t ws_size,
                              hipStream_t stream) {
    const float* feat = (const float*)d_in[0];
    float* out = (float*)d_out;

    unsigned short* X = (unsigned short*)d_ws;
    float* S = (float*)((char*)d_ws + (size_t)N_ROWS * D_DIM * 2);
    float* rawp = S + N_ROWS;

    normalize_kernel<<<N_ROWS / 4, 256, 0, stream>>>(feat, X, S, out);
    pos_kernel<<<N_ROWS / 4, 256, 0, stream>>>(X, rawp);
    sim_lse_kernel<<<dim3(N_ROWS / ROWS_PER_BLOCK, COL_SPLITS), 256, 0, stream>>>(X, S);
    finalize_kernel<<<N_ROWS / 256, 256, 0, stream>>>(S, rawp, out);
}